// Round 4
// baseline (174.551 us; speedup 1.0000x reference)
//
#include <hip/hip_runtime.h>

#define KSZ 11
#define HALO 5
#define TW 32                 /* tile width (output cols)  */
#define TH 30                 /* tile height (output rows) */
#define SMW (TW + 2 * HALO)   /* 42 staged cols */
#define SMH (TH + 2 * HALO)   /* 40 staged rows */
#define LSTR 43               /* odd float2 row stride: conflict-free */
#define THREADS 320           /* = SMH*8 -> H-pass exactly 1 iter */

// Normalized 1-D Gaussian, sigma=1.5, K=11.
#define W0 1.0283800e-03f
#define W1 7.5987000e-03f
#define W2 3.6000800e-02f
#define W3 1.0936070e-01f
#define W4 2.1300550e-01f
#define W5 2.6601170e-01f

__global__ __launch_bounds__(THREADS, 5) void ssim_tile_kernel(
    const float* __restrict__ x, const float* __restrict__ y,
    float* __restrict__ partial, int W, int H)
{
    // 4 blurred signals: ux, uy, p = x^2+y^2, q = x*y
    __shared__ float2 lxy[SMH * LSTR];                   // 13.75 KB
    __shared__ __align__(16) float hbuf[4][SMH * TW];    // 20.5 KB
    __shared__ float wsum[THREADS / 64];

    const float w[KSZ] = {W0, W1, W2, W3, W4, W5, W4, W3, W2, W1, W0};

    const int tid = threadIdx.x;
    const int tilesPerRow = W / TW;                       // 16
    const int tileR = (blockIdx.x / tilesPerRow) * TH;
    const int tileC = (blockIdx.x % tilesPerRow) * TW;
    const size_t base = (size_t)blockIdx.y * (size_t)W * (size_t)H;

    // ---- Stage raw x,y tile (with halo) as interleaved float2 ----
    const bool interior = (tileR >= HALO) && (tileR + TH + HALO <= H) &&
                          (tileC >= HALO) && (tileC + TW + HALO <= W);
    if (interior) {
        const float* xb = x + base + (size_t)(tileR - HALO) * W + (tileC - HALO);
        const float* yb = y + base + (size_t)(tileR - HALO) * W + (tileC - HALO);
        for (int i = tid; i < SMH * SMW; i += THREADS) {
            int r = i / SMW, c = i - r * SMW;
            int g = r * W + c;
            lxy[r * LSTR + c] = make_float2(xb[g], yb[g]);
        }
    } else {
        for (int i = tid; i < SMH * SMW; i += THREADS) {
            int r = i / SMW, c = i - r * SMW;
            int gr = tileR - HALO + r;
            int gc = tileC - HALO + c;
            float vx = 0.f, vy = 0.f;
            if (gr >= 0 && gr < H && gc >= 0 && gc < W) {
                size_t off = base + (size_t)gr * W + (size_t)gc;
                vx = x[off];
                vy = y[off];
            }
            lxy[r * LSTR + c] = make_float2(vx, vy);
        }
    }
    __syncthreads();

    // ---- Horizontal pass: 4 signals fused; exactly 320 items, no loop ----
    // item = (row r in [0,40), col-group c0 in {0,4,...,28})
    {
        const int r = tid >> 3;
        const int c0 = (tid & 7) << 2;
        const float2* row = &lxy[r * LSTR + c0];

        float2 v[14];
#pragma unroll
        for (int k = 0; k < 14; ++k) v[k] = row[k];
        float pp[14], qq[14];
#pragma unroll
        for (int k = 0; k < 14; ++k) {
            pp[k] = v[k].x * v[k].x + v[k].y * v[k].y;
            qq[k] = v[k].x * v[k].y;
        }

        float s0[4] = {0, 0, 0, 0}, s1[4] = {0, 0, 0, 0};
        float s2[4] = {0, 0, 0, 0}, s3[4] = {0, 0, 0, 0};
#pragma unroll
        for (int k = 0; k < KSZ; ++k) {
#pragma unroll
            for (int j = 0; j < 4; ++j) {
                s0[j] += w[k] * v[k + j].x;
                s1[j] += w[k] * v[k + j].y;
                s2[j] += w[k] * pp[k + j];
                s3[j] += w[k] * qq[k + j];
            }
        }
        int o = r * TW + c0;
        *(float4*)&hbuf[0][o] = make_float4(s0[0], s0[1], s0[2], s0[3]);
        *(float4*)&hbuf[1][o] = make_float4(s1[0], s1[1], s1[2], s1[3]);
        *(float4*)&hbuf[2][o] = make_float4(s2[0], s2[1], s2[2], s2[3]);
        *(float4*)&hbuf[3][o] = make_float4(s3[0], s3[1], s3[2], s3[3]);
    }
    __syncthreads();

    // ---- Vertical pass: thread owns (col c, rows r0..r0+2) exactly ----
    const int c = tid & (TW - 1);
    const int r0 = (tid >> 5) * 3;

    float acc[4][3];
#pragma unroll
    for (int s = 0; s < 4; ++s) {
        float win[13];
#pragma unroll
        for (int k = 0; k < 13; ++k) win[k] = hbuf[s][(r0 + k) * TW + c];
#pragma unroll
        for (int j = 0; j < 3; ++j) {
            float t = 0.f;
#pragma unroll
            for (int k = 0; k < KSZ; ++k) t += w[k] * win[j + k];
            acc[s][j] = t;
        }
    }

    // ---- SSIM map + per-thread sum (mask rows past image bottom) ----
    const float c1 = 0.01f * 0.01f;
    const float c2 = 0.03f * 0.03f;
    float bsum = 0.f;
#pragma unroll
    for (int j = 0; j < 3; ++j) {
        float ux = acc[0][j], uy = acc[1][j];
        float up = acc[2][j], uq = acc[3][j];
        float sumsq = ux * ux + uy * uy;
        float vsum = up - sumsq;                 // vx + vy
        float vxy = uq - ux * uy;
        float num = (2.f * ux * uy + c1) * (2.f * vxy + c2);
        float den = (sumsq + c1) * (vsum + c2);
        float s = num * __builtin_amdgcn_rcpf(den + 1e-12f);
        bsum += (tileR + r0 + j < H) ? s : 0.f;
    }

    // ---- Wave shuffle reduce, cross-wave via LDS ----
#pragma unroll
    for (int off = 32; off > 0; off >>= 1) bsum += __shfl_down(bsum, off, 64);
    int lane = tid & 63, wid = tid >> 6;
    if (lane == 0) wsum[wid] = bsum;
    __syncthreads();
    if (tid == 0) {
        float tot = 0.f;
#pragma unroll
        for (int i = 0; i < THREADS / 64; ++i) tot += wsum[i];
        partial[(size_t)blockIdx.y * gridDim.x + blockIdx.x] = tot;
    }
}

// Final deterministic reduction: n partials -> out[0] = 1 - sum/count
__global__ __launch_bounds__(256) void ssim_reduce_kernel(
    const float* __restrict__ partial, int n, float* __restrict__ out,
    double inv_count)
{
    __shared__ double ws[4];
    double s = 0.0;
    for (int i = threadIdx.x; i < n; i += 256) s += (double)partial[i];
#pragma unroll
    for (int off = 32; off > 0; off >>= 1) s += __shfl_down(s, off, 64);
    int lane = threadIdx.x & 63, wid = threadIdx.x >> 6;
    if (lane == 0) ws[wid] = s;
    __syncthreads();
    if (threadIdx.x == 0) {
        double tot = ws[0] + ws[1] + ws[2] + ws[3];
        out[0] = (float)(1.0 - tot * inv_count);
    }
}

extern "C" void kernel_launch(void* const* d_in, const int* in_sizes, int n_in,
                              void* d_out, int out_size, void* d_ws, size_t ws_size,
                              hipStream_t stream) {
    const float* x = (const float*)d_in[0];
    const float* y = (const float*)d_in[1];
    float* partial = (float*)d_ws;

    const int W = 512, H = 512;
    const int N = 32, C = 2;
    const int tilesX = W / TW;                  // 16
    const int tilesY = (H + TH - 1) / TH;       // 18
    const int tilesPerPlane = tilesX * tilesY;  // 288
    const int planes = N * C;                   // 64

    dim3 grid(tilesPerPlane, planes);
    ssim_tile_kernel<<<grid, THREADS, 0, stream>>>(x, y, partial, W, H);

    const int nPartial = tilesPerPlane * planes; // 18432
    const double inv_count = 1.0 / ((double)N * C * W * H);
    ssim_reduce_kernel<<<1, 256, 0, stream>>>(partial, nPartial, (float*)d_out,
                                              inv_count);
}

// Round 5
// 165.826 us; speedup vs baseline: 1.0526x; 1.0526x over previous
//
#include <hip/hip_runtime.h>

#define KSZ 11
#define HALO 5
#define TW 32                 /* tile width (output cols)  */
#define TH 30                 /* tile height (output rows) */
#define SMW (TW + 2 * HALO)   /* 42 staged cols */
#define SMH (TH + 2 * HALO)   /* 40 staged rows */
#define LSTR 43               /* odd float2 row stride: conflict-free */
#define THREADS 320           /* = SMH*8 -> H-pass exactly 1 iter */

// Normalized 1-D Gaussian, sigma=1.5, K=11.
#define W0 1.0283800e-03f
#define W1 7.5987000e-03f
#define W2 3.6000800e-02f
#define W3 1.0936070e-01f
#define W4 2.1300550e-01f
#define W5 2.6601170e-01f

// NOTE: no min-waves arg! Round-4's (320,5) forced VGPR=48 -> scratch spills
// (WRITE_SIZE 0.5MB -> 37MB) and a 27% regression. Let the allocator float.
__global__ __launch_bounds__(THREADS) void ssim_tile_kernel(
    const float* __restrict__ x, const float* __restrict__ y,
    float* __restrict__ partial, int W, int H)
{
    // 4 blurred signals: ux, uy, p = x^2+y^2, q = x*y
    __shared__ float2 lxy[SMH * LSTR];                   // 13.75 KB
    __shared__ __align__(16) float hbuf[4][SMH * TW];    // 20.5 KB
    __shared__ float wsum[THREADS / 64];

    const float w[KSZ] = {W0, W1, W2, W3, W4, W5, W4, W3, W2, W1, W0};

    const int tid = threadIdx.x;
    const int tilesPerRow = W / TW;                       // 16
    const int tileR = (blockIdx.x / tilesPerRow) * TH;
    const int tileC = (blockIdx.x % tilesPerRow) * TW;
    const size_t base = (size_t)blockIdx.y * (size_t)W * (size_t)H;

    // ---- Stage raw x,y tile (with halo) as interleaved float2 ----
    const bool interior = (tileR >= HALO) && (tileR + TH + HALO <= H) &&
                          (tileC >= HALO) && (tileC + TW + HALO <= W);
    if (interior) {
        const float* xb = x + base + (size_t)(tileR - HALO) * W + (tileC - HALO);
        const float* yb = y + base + (size_t)(tileR - HALO) * W + (tileC - HALO);
        for (int i = tid; i < SMH * SMW; i += THREADS) {
            int r = i / SMW, c = i - r * SMW;
            int g = r * W + c;
            lxy[r * LSTR + c] = make_float2(xb[g], yb[g]);
        }
    } else {
        for (int i = tid; i < SMH * SMW; i += THREADS) {
            int r = i / SMW, c = i - r * SMW;
            int gr = tileR - HALO + r;
            int gc = tileC - HALO + c;
            float vx = 0.f, vy = 0.f;
            if (gr >= 0 && gr < H && gc >= 0 && gc < W) {
                size_t off = base + (size_t)gr * W + (size_t)gc;
                vx = x[off];
                vy = y[off];
            }
            lxy[r * LSTR + c] = make_float2(vx, vy);
        }
    }
    __syncthreads();

    // ---- Horizontal pass: 4 signals fused; exactly 320 items, no loop ----
    // item = (row r in [0,40), col-group c0 in {0,4,...,28})
    {
        const int r = tid >> 3;
        const int c0 = (tid & 7) << 2;
        const float2* row = &lxy[r * LSTR + c0];

        float2 v[14];
#pragma unroll
        for (int k = 0; k < 14; ++k) v[k] = row[k];
        float pp[14], qq[14];
#pragma unroll
        for (int k = 0; k < 14; ++k) {
            pp[k] = v[k].x * v[k].x + v[k].y * v[k].y;
            qq[k] = v[k].x * v[k].y;
        }

        float s0[4] = {0, 0, 0, 0}, s1[4] = {0, 0, 0, 0};
        float s2[4] = {0, 0, 0, 0}, s3[4] = {0, 0, 0, 0};
#pragma unroll
        for (int k = 0; k < KSZ; ++k) {
#pragma unroll
            for (int j = 0; j < 4; ++j) {
                s0[j] += w[k] * v[k + j].x;
                s1[j] += w[k] * v[k + j].y;
                s2[j] += w[k] * pp[k + j];
                s3[j] += w[k] * qq[k + j];
            }
        }
        int o = r * TW + c0;
        *(float4*)&hbuf[0][o] = make_float4(s0[0], s0[1], s0[2], s0[3]);
        *(float4*)&hbuf[1][o] = make_float4(s1[0], s1[1], s1[2], s1[3]);
        *(float4*)&hbuf[2][o] = make_float4(s2[0], s2[1], s2[2], s2[3]);
        *(float4*)&hbuf[3][o] = make_float4(s3[0], s3[1], s3[2], s3[3]);
    }
    __syncthreads();

    // ---- Vertical pass: thread owns (col c, rows r0..r0+2) exactly ----
    const int c = tid & (TW - 1);
    const int r0 = (tid >> 5) * 3;

    float acc[4][3];
#pragma unroll
    for (int s = 0; s < 4; ++s) {
        float win[13];
#pragma unroll
        for (int k = 0; k < 13; ++k) win[k] = hbuf[s][(r0 + k) * TW + c];
#pragma unroll
        for (int j = 0; j < 3; ++j) {
            float t = 0.f;
#pragma unroll
            for (int k = 0; k < KSZ; ++k) t += w[k] * win[j + k];
            acc[s][j] = t;
        }
    }

    // ---- SSIM map + per-thread sum (mask rows past image bottom) ----
    const float c1 = 0.01f * 0.01f;
    const float c2 = 0.03f * 0.03f;
    float bsum = 0.f;
#pragma unroll
    for (int j = 0; j < 3; ++j) {
        float ux = acc[0][j], uy = acc[1][j];
        float up = acc[2][j], uq = acc[3][j];
        float sumsq = ux * ux + uy * uy;
        float vsum = up - sumsq;                 // vx + vy
        float vxy = uq - ux * uy;
        float num = (2.f * ux * uy + c1) * (2.f * vxy + c2);
        float den = (sumsq + c1) * (vsum + c2);
        float s = num * __builtin_amdgcn_rcpf(den + 1e-12f);
        bsum += (tileR + r0 + j < H) ? s : 0.f;
    }

    // ---- Wave shuffle reduce, cross-wave via LDS ----
#pragma unroll
    for (int off = 32; off > 0; off >>= 1) bsum += __shfl_down(bsum, off, 64);
    int lane = tid & 63, wid = tid >> 6;
    if (lane == 0) wsum[wid] = bsum;
    __syncthreads();
    if (tid == 0) {
        float tot = 0.f;
#pragma unroll
        for (int i = 0; i < THREADS / 64; ++i) tot += wsum[i];
        partial[(size_t)blockIdx.y * gridDim.x + blockIdx.x] = tot;
    }
}

// Final deterministic reduction: n partials -> out[0] = 1 - sum/count
__global__ __launch_bounds__(256) void ssim_reduce_kernel(
    const float* __restrict__ partial, int n, float* __restrict__ out,
    double inv_count)
{
    __shared__ double ws[4];
    double s = 0.0;
    for (int i = threadIdx.x; i < n; i += 256) s += (double)partial[i];
#pragma unroll
    for (int off = 32; off > 0; off >>= 1) s += __shfl_down(s, off, 64);
    int lane = threadIdx.x & 63, wid = threadIdx.x >> 6;
    if (lane == 0) ws[wid] = s;
    __syncthreads();
    if (threadIdx.x == 0) {
        double tot = ws[0] + ws[1] + ws[2] + ws[3];
        out[0] = (float)(1.0 - tot * inv_count);
    }
}

extern "C" void kernel_launch(void* const* d_in, const int* in_sizes, int n_in,
                              void* d_out, int out_size, void* d_ws, size_t ws_size,
                              hipStream_t stream) {
    const float* x = (const float*)d_in[0];
    const float* y = (const float*)d_in[1];
    float* partial = (float*)d_ws;

    const int W = 512, H = 512;
    const int N = 32, C = 2;
    const int tilesX = W / TW;                  // 16
    const int tilesY = (H + TH - 1) / TH;       // 18
    const int tilesPerPlane = tilesX * tilesY;  // 288
    const int planes = N * C;                   // 64

    dim3 grid(tilesPerPlane, planes);
    ssim_tile_kernel<<<grid, THREADS, 0, stream>>>(x, y, partial, W, H);

    const int nPartial = tilesPerPlane * planes; // 18432
    const double inv_count = 1.0 / ((double)N * C * W * H);
    ssim_reduce_kernel<<<1, 256, 0, stream>>>(partial, nPartial, (float*)d_out,
                                              inv_count);
}

// Round 6
// 119.921 us; speedup vs baseline: 1.4555x; 1.3828x over previous
//
#include <hip/hip_runtime.h>
#include <hip/hip_fp16.h>

#define KSZ 11
#define HALO 5
#define TILE 32
#define SMW 42                /* staged cols = TILE + 2*HALO */
#define SMH 42                /* staged rows */
#define LSTR 43               /* odd half2 row stride: conflict-free b32 */
#define THREADS 256

// Normalized 1-D Gaussian, sigma=1.5, K=11.
#define W0 1.0283800e-03f
#define W1 7.5987000e-03f
#define W2 3.6000800e-02f
#define W3 1.0936070e-01f
#define W4 2.1300550e-01f
#define W5 2.6601170e-01f

// 256 threads / 32x32 tile (R3-proven shape, VGPR=64 codegen).
// lxy staged as packed half2 -> LDS ~28.7KB -> 5 blocks/CU (20 waves).
__global__ __launch_bounds__(THREADS) void ssim_tile_kernel(
    const float* __restrict__ x, const float* __restrict__ y,
    float* __restrict__ partial, int W, int H)
{
    __shared__ __half2 lxy[SMH * LSTR];                  // 7.2 KB
    __shared__ __align__(16) float hbuf[4][SMH * TILE];  // 21.5 KB
    __shared__ float wsum[THREADS / 64];

    const float w[KSZ] = {W0, W1, W2, W3, W4, W5, W4, W3, W2, W1, W0};

    const int tid = threadIdx.x;
    const int tilesPerRow = W / TILE;
    const int tileR = (blockIdx.x / tilesPerRow) * TILE;
    const int tileC = (blockIdx.x % tilesPerRow) * TILE;
    const size_t base = (size_t)blockIdx.y * (size_t)W * (size_t)H;

    // ---- Stage raw x,y (with halo) as packed half2; exact 252x7 map ----
    // 42x42 = 1764 = 252 * 7; one div at entry, r += 6 per iter.
    const bool interior = (tileR >= HALO) && (tileR + TILE + HALO <= H) &&
                          (tileC >= HALO) && (tileC + TILE + HALO <= W);
    if (tid < 252) {
        const int c = tid % SMW;
        const int rs = tid / SMW;
        if (interior) {
            const float* xb = x + base + (size_t)(tileR - HALO) * W + (tileC - HALO);
            const float* yb = y + base + (size_t)(tileR - HALO) * W + (tileC - HALO);
#pragma unroll
            for (int it = 0; it < 7; ++it) {
                int r = rs + it * 6;
                int g = r * W + c;
                lxy[r * LSTR + c] = __floats2half2_rn(xb[g], yb[g]);
            }
        } else {
#pragma unroll
            for (int it = 0; it < 7; ++it) {
                int r = rs + it * 6;
                int gr = tileR - HALO + r;
                int gc = tileC - HALO + c;
                float vx = 0.f, vy = 0.f;
                if (gr >= 0 && gr < H && gc >= 0 && gc < W) {
                    size_t off = base + (size_t)gr * W + (size_t)gc;
                    vx = x[off];
                    vy = y[off];
                }
                lxy[r * LSTR + c] = __floats2half2_rn(vx, vy);
            }
        }
    }
    __syncthreads();

    // ---- Horizontal pass: 4 signals fused, 4 consecutive cols/item ----
    // 42 rows x 8 col-groups = 336 items over 256 threads.
    for (int wi = tid; wi < SMH * 8; wi += THREADS) {
        int r = wi >> 3;
        int c0 = (wi & 7) << 2;
        const __half2* row = &lxy[r * LSTR + c0];

        float2 v[14];
#pragma unroll
        for (int k = 0; k < 14; ++k) v[k] = __half22float2(row[k]);
        float pp[14], qq[14];
#pragma unroll
        for (int k = 0; k < 14; ++k) {
            pp[k] = v[k].x * v[k].x + v[k].y * v[k].y;
            qq[k] = v[k].x * v[k].y;
        }

        float s0[4] = {0, 0, 0, 0}, s1[4] = {0, 0, 0, 0};
        float s2[4] = {0, 0, 0, 0}, s3[4] = {0, 0, 0, 0};
#pragma unroll
        for (int k = 0; k < KSZ; ++k) {
#pragma unroll
            for (int j = 0; j < 4; ++j) {
                s0[j] += w[k] * v[k + j].x;
                s1[j] += w[k] * v[k + j].y;
                s2[j] += w[k] * pp[k + j];
                s3[j] += w[k] * qq[k + j];
            }
        }
        int o = r * TILE + c0;
        *(float4*)&hbuf[0][o] = make_float4(s0[0], s0[1], s0[2], s0[3]);
        *(float4*)&hbuf[1][o] = make_float4(s1[0], s1[1], s1[2], s1[3]);
        *(float4*)&hbuf[2][o] = make_float4(s2[0], s2[1], s2[2], s2[3]);
        *(float4*)&hbuf[3][o] = make_float4(s3[0], s3[1], s3[2], s3[3]);
    }
    __syncthreads();

    // ---- Vertical pass: thread owns (col c, rows r0..r0+3) exactly ----
    const int c = tid & (TILE - 1);
    const int r0 = (tid >> 5) << 2;

    float acc[4][4];
#pragma unroll
    for (int s = 0; s < 4; ++s) {
        float win[14];
#pragma unroll
        for (int k = 0; k < 14; ++k) win[k] = hbuf[s][(r0 + k) * TILE + c];
#pragma unroll
        for (int j = 0; j < 4; ++j) {
            float t = 0.f;
#pragma unroll
            for (int k = 0; k < KSZ; ++k) t += w[k] * win[j + k];
            acc[s][j] = t;
        }
    }

    // ---- SSIM map + per-thread sum ----
    const float c1 = 0.01f * 0.01f;
    const float c2 = 0.03f * 0.03f;
    float bsum = 0.f;
#pragma unroll
    for (int j = 0; j < 4; ++j) {
        float ux = acc[0][j], uy = acc[1][j];
        float up = acc[2][j], uq = acc[3][j];
        float sumsq = ux * ux + uy * uy;
        float vsum = up - sumsq;                 // vx + vy
        float vxy = uq - ux * uy;
        float num = (2.f * ux * uy + c1) * (2.f * vxy + c2);
        float den = (sumsq + c1) * (vsum + c2);
        bsum += num * __builtin_amdgcn_rcpf(den + 1e-12f);
    }

    // ---- Wave shuffle reduce, cross-wave via LDS ----
#pragma unroll
    for (int off = 32; off > 0; off >>= 1) bsum += __shfl_down(bsum, off, 64);
    int lane = tid & 63, wid = tid >> 6;
    if (lane == 0) wsum[wid] = bsum;
    __syncthreads();
    if (tid == 0) {
        float tot = 0.f;
#pragma unroll
        for (int i = 0; i < THREADS / 64; ++i) tot += wsum[i];
        partial[(size_t)blockIdx.y * gridDim.x + blockIdx.x] = tot;
    }
}

// Final deterministic reduction: n partials -> out[0] = 1 - sum/count
__global__ __launch_bounds__(256) void ssim_reduce_kernel(
    const float* __restrict__ partial, int n, float* __restrict__ out,
    double inv_count)
{
    __shared__ double ws[4];
    double s = 0.0;
    for (int i = threadIdx.x; i < n; i += 256) s += (double)partial[i];
#pragma unroll
    for (int off = 32; off > 0; off >>= 1) s += __shfl_down(s, off, 64);
    int lane = threadIdx.x & 63, wid = threadIdx.x >> 6;
    if (lane == 0) ws[wid] = s;
    __syncthreads();
    if (threadIdx.x == 0) {
        double tot = ws[0] + ws[1] + ws[2] + ws[3];
        out[0] = (float)(1.0 - tot * inv_count);
    }
}

extern "C" void kernel_launch(void* const* d_in, const int* in_sizes, int n_in,
                              void* d_out, int out_size, void* d_ws, size_t ws_size,
                              hipStream_t stream) {
    const float* x = (const float*)d_in[0];
    const float* y = (const float*)d_in[1];
    float* partial = (float*)d_ws;

    const int W = 512, H = 512;
    const int N = 32, C = 2;
    const int tilesPerPlane = (W / TILE) * (H / TILE); // 256
    const int planes = N * C;                          // 64

    dim3 grid(tilesPerPlane, planes);
    ssim_tile_kernel<<<grid, THREADS, 0, stream>>>(x, y, partial, W, H);

    const int nPartial = tilesPerPlane * planes; // 16384
    const double inv_count = 1.0 / ((double)N * C * W * H);
    ssim_reduce_kernel<<<1, 256, 0, stream>>>(partial, nPartial, (float*)d_out,
                                              inv_count);
}

// Round 7
// 81.349 us; speedup vs baseline: 2.1457x; 1.4742x over previous
//
#include <hip/hip_runtime.h>
#include <hip/hip_fp16.h>

#define KSZ 11
#define HALO 5
#define TILE 32
#define SMW 42                /* staged cols = TILE + 2*HALO */
#define SMH 42                /* staged rows */
#define LSTR 43               /* odd row stride (b32 units): conflict-free */
#define THREADS 256

// Normalized 1-D Gaussian, sigma=1.5, K=11.
#define W0 1.0283800e-03f
#define W1 7.5987000e-03f
#define W2 3.6000800e-02f
#define W3 1.0936070e-01f
#define W4 2.1300550e-01f
#define W5 2.6601170e-01f

// Channel-packed SSIM: both C=2 channels of one (n, 32x32 tile) per block,
// packed in half2 lanes -> every blur FMA is v_pk_fma_f16 (2 ch/instr).
// Blocks halve vs R6 at ~constant per-block VALU. SSIM math stays f32.
__global__ __launch_bounds__(THREADS) void ssim_tile_kernel(
    const float* __restrict__ x, const float* __restrict__ y,
    float* __restrict__ partial, int W, int H)
{
    __shared__ __half2 lxx[SMH * LSTR];                    // 7.2 KB (x: ch0,ch1)
    __shared__ __half2 lyy[SMH * LSTR];                    // 7.2 KB (y: ch0,ch1)
    __shared__ __align__(16) __half2 hbuf[4][SMH * TILE];  // 21.5 KB
    __shared__ float wsum[THREADS / 64];

    const float wf[KSZ] = {W0, W1, W2, W3, W4, W5, W4, W3, W2, W1, W0};
    __half2 w2[KSZ];
#pragma unroll
    for (int k = 0; k < KSZ; ++k) w2[k] = __float2half2_rn(wf[k]);
    const __half2 hz = __float2half2_rn(0.0f);

    const int tid = threadIdx.x;
    const int tilesPerRow = W / TILE;
    const int tileR = (blockIdx.x / tilesPerRow) * TILE;
    const int tileC = (blockIdx.x % tilesPerRow) * TILE;
    const size_t plane = (size_t)W * (size_t)H;
    const size_t base0 = (size_t)blockIdx.y * 2 * plane;   // channel 0
    const size_t base1 = base0 + plane;                    // channel 1

    // ---- Stage x,y (both channels, with halo); exact 252x7 map ----
    const bool interior = (tileR >= HALO) && (tileR + TILE + HALO <= H) &&
                          (tileC >= HALO) && (tileC + TILE + HALO <= W);
    if (tid < 252) {
        const int c = tid % SMW;
        const int rs = tid / SMW;
        if (interior) {
            const size_t org = (size_t)(tileR - HALO) * W + (tileC - HALO);
#pragma unroll
            for (int it = 0; it < 7; ++it) {
                int r = rs + it * 6;
                size_t g = org + (size_t)r * W + c;
                lxx[r * LSTR + c] = __floats2half2_rn(x[base0 + g], x[base1 + g]);
                lyy[r * LSTR + c] = __floats2half2_rn(y[base0 + g], y[base1 + g]);
            }
        } else {
#pragma unroll
            for (int it = 0; it < 7; ++it) {
                int r = rs + it * 6;
                int gr = tileR - HALO + r;
                int gc = tileC - HALO + c;
                float x0 = 0.f, x1 = 0.f, y0 = 0.f, y1 = 0.f;
                if (gr >= 0 && gr < H && gc >= 0 && gc < W) {
                    size_t g = (size_t)gr * W + (size_t)gc;
                    x0 = x[base0 + g]; x1 = x[base1 + g];
                    y0 = y[base0 + g]; y1 = y[base1 + g];
                }
                lxx[r * LSTR + c] = __floats2half2_rn(x0, x1);
                lyy[r * LSTR + c] = __floats2half2_rn(y0, y1);
            }
        }
    }
    __syncthreads();

    // ---- Horizontal pass: 4 packed signals, 4 consecutive cols/item ----
    for (int wi = tid; wi < SMH * 8; wi += THREADS) {
        int r = wi >> 3;
        int c0 = (wi & 7) << 2;
        const __half2* rx = &lxx[r * LSTR + c0];
        const __half2* ry = &lyy[r * LSTR + c0];

        __half2 vx[14], vy[14];
#pragma unroll
        for (int k = 0; k < 14; ++k) { vx[k] = rx[k]; vy[k] = ry[k]; }
        __half2 pp[14], qq[14];
#pragma unroll
        for (int k = 0; k < 14; ++k) {
            pp[k] = __hfma2(vy[k], vy[k], __hmul2(vx[k], vx[k])); // x^2+y^2
            qq[k] = __hmul2(vx[k], vy[k]);                        // x*y
        }

        __half2 s0[4] = {hz, hz, hz, hz}, s1[4] = {hz, hz, hz, hz};
        __half2 s2[4] = {hz, hz, hz, hz}, s3[4] = {hz, hz, hz, hz};
#pragma unroll
        for (int k = 0; k < KSZ; ++k) {
#pragma unroll
            for (int j = 0; j < 4; ++j) {
                s0[j] = __hfma2(w2[k], vx[k + j], s0[j]);
                s1[j] = __hfma2(w2[k], vy[k + j], s1[j]);
                s2[j] = __hfma2(w2[k], pp[k + j], s2[j]);
                s3[j] = __hfma2(w2[k], qq[k + j], s3[j]);
            }
        }
        int o = r * TILE + c0;   // c0 % 4 == 0 -> 16B aligned
        *(float4*)&hbuf[0][o] = *(const float4*)s0;
        *(float4*)&hbuf[1][o] = *(const float4*)s1;
        *(float4*)&hbuf[2][o] = *(const float4*)s2;
        *(float4*)&hbuf[3][o] = *(const float4*)s3;
    }
    __syncthreads();

    // ---- Vertical pass: thread owns (col c, rows r0..r0+3) ----
    const int c = tid & (TILE - 1);
    const int r0 = (tid >> 5) << 2;

    __half2 acc[4][4];
#pragma unroll
    for (int s = 0; s < 4; ++s) {
        __half2 win[14];
#pragma unroll
        for (int k = 0; k < 14; ++k) win[k] = hbuf[s][(r0 + k) * TILE + c];
#pragma unroll
        for (int j = 0; j < 4; ++j) {
            __half2 t = hz;
#pragma unroll
            for (int k = 0; k < KSZ; ++k) t = __hfma2(w2[k], win[j + k], t);
            acc[s][j] = t;
        }
    }

    // ---- SSIM map (f32, per channel) + per-thread sum ----
    const float c1 = 0.01f * 0.01f;
    const float c2 = 0.03f * 0.03f;
    float bsum = 0.f;
#pragma unroll
    for (int j = 0; j < 4; ++j) {
        float2 ux2 = __half22float2(acc[0][j]);
        float2 uy2 = __half22float2(acc[1][j]);
        float2 up2 = __half22float2(acc[2][j]);
        float2 uq2 = __half22float2(acc[3][j]);
#pragma unroll
        for (int ch = 0; ch < 2; ++ch) {
            float ux = ch ? ux2.y : ux2.x;
            float uy = ch ? uy2.y : uy2.x;
            float up = ch ? up2.y : up2.x;
            float uq = ch ? uq2.y : uq2.x;
            float sumsq = ux * ux + uy * uy;
            float vsum = up - sumsq;             // vx + vy
            float vxy = uq - ux * uy;
            float num = (2.f * ux * uy + c1) * (2.f * vxy + c2);
            float den = (sumsq + c1) * (vsum + c2);
            bsum += num * __builtin_amdgcn_rcpf(den + 1e-12f);
        }
    }

    // ---- Wave shuffle reduce, cross-wave via LDS ----
#pragma unroll
    for (int off = 32; off > 0; off >>= 1) bsum += __shfl_down(bsum, off, 64);
    int lane = tid & 63, wid = tid >> 6;
    if (lane == 0) wsum[wid] = bsum;
    __syncthreads();
    if (tid == 0) {
        float tot = 0.f;
#pragma unroll
        for (int i = 0; i < THREADS / 64; ++i) tot += wsum[i];
        partial[(size_t)blockIdx.y * gridDim.x + blockIdx.x] = tot;
    }
}

// Final deterministic reduction: n partials -> out[0] = 1 - sum/count
__global__ __launch_bounds__(256) void ssim_reduce_kernel(
    const float* __restrict__ partial, int n, float* __restrict__ out,
    double inv_count)
{
    __shared__ double ws[4];
    double s = 0.0;
    for (int i = threadIdx.x; i < n; i += 256) s += (double)partial[i];
#pragma unroll
    for (int off = 32; off > 0; off >>= 1) s += __shfl_down(s, off, 64);
    int lane = threadIdx.x & 63, wid = threadIdx.x >> 6;
    if (lane == 0) ws[wid] = s;
    __syncthreads();
    if (threadIdx.x == 0) {
        double tot = ws[0] + ws[1] + ws[2] + ws[3];
        out[0] = (float)(1.0 - tot * inv_count);
    }
}

extern "C" void kernel_launch(void* const* d_in, const int* in_sizes, int n_in,
                              void* d_out, int out_size, void* d_ws, size_t ws_size,
                              hipStream_t stream) {
    const float* x = (const float*)d_in[0];
    const float* y = (const float*)d_in[1];
    float* partial = (float*)d_ws;

    const int W = 512, H = 512;
    const int N = 32, C = 2;
    const int tilesPerPlane = (W / TILE) * (H / TILE); // 256
    // grid.y = N (batch); both channels packed per block.

    dim3 grid(tilesPerPlane, N);
    ssim_tile_kernel<<<grid, THREADS, 0, stream>>>(x, y, partial, W, H);

    const int nPartial = tilesPerPlane * N; // 8192
    const double inv_count = 1.0 / ((double)N * C * W * H);
    ssim_reduce_kernel<<<1, 256, 0, stream>>>(partial, nPartial, (float*)d_out,
                                              inv_count);
}